// Round 1
// baseline (688.396 us; speedup 1.0000x reference)
//
#include <hip/hip_runtime.h>

#define LQ 12000
#define IN_D 1024
#define DM 128
#define EDM 256
#define NS 16
#define DTR 8
#define NCHUNK 120
#define CSZ 100
#define NCH 4096  // EDM*NS

__device__ __forceinline__ float wave_sum64(float v) {
#pragma unroll
  for (int o = 32; o > 0; o >>= 1) v += __shfl_xor(v, o);
  return v;
}
__device__ __forceinline__ float wave_max64(float v) {
#pragma unroll
  for (int o = 32; o > 0; o >>= 1) v = fmaxf(v, __shfl_xor(v, o));
  return v;
}

// ---------------- generic fp32 GEMM: C = act(A@B + bias) or C += A@B ----------------
// A: MxK row-major, B: KxN row-major, C: MxN row-major. K % 16 == 0.
// ACT: 0 none, 1 gelu(exact), 2 tanh
template <int ACT, bool BIAS, bool ACCUM>
__global__ __launch_bounds__(256) void gemm_k(const float* __restrict__ A,
                                              const float* __restrict__ B,
                                              const float* __restrict__ bias,
                                              float* __restrict__ C, int M, int N,
                                              int K) {
  __shared__ __align__(16) float As[16][68];  // As[k][m]
  __shared__ __align__(16) float Bs[16][68];  // Bs[k][n]
  const int tid = threadIdx.x;
  const int tx = tid & 15, ty = tid >> 4;
  const int row0 = blockIdx.y * 64, col0 = blockIdx.x * 64;
  // A-tile load mapping: 64 rows x 16 k, float4 along k
  const int a_row = tid >> 2;
  const int a_k = (tid & 3) * 4;
  // B-tile load mapping: 16 k x 64 cols, float4 along n
  const int b_k = tid >> 4;
  const int b_col = (tid & 15) * 4;
  float acc[4][4] = {};
  int ar = row0 + a_row;
  if (ar > M - 1) ar = M - 1;  // clamp; stores are masked
  const float* Abase = A + (size_t)ar * K + a_k;
  for (int kt = 0; kt < K; kt += 16) {
    float4 av = *(const float4*)(Abase + kt);
    As[a_k + 0][a_row] = av.x;
    As[a_k + 1][a_row] = av.y;
    As[a_k + 2][a_row] = av.z;
    As[a_k + 3][a_row] = av.w;
    int bc = col0 + b_col;
    const float* bp = B + (size_t)(kt + b_k) * N + bc;
    float4 bv;
    if (bc + 3 < N) {
      bv = *(const float4*)bp;
    } else {
      bv.x = (bc + 0 < N) ? bp[0] : 0.f;
      bv.y = (bc + 1 < N) ? bp[1] : 0.f;
      bv.z = (bc + 2 < N) ? bp[2] : 0.f;
      bv.w = (bc + 3 < N) ? bp[3] : 0.f;
    }
    *(float4*)&Bs[b_k][b_col] = bv;
    __syncthreads();
#pragma unroll
    for (int k = 0; k < 16; ++k) {
      float4 a4 = *(const float4*)&As[k][ty * 4];
      float4 b4 = *(const float4*)&Bs[k][tx * 4];
      float am[4] = {a4.x, a4.y, a4.z, a4.w};
      float bm[4] = {b4.x, b4.y, b4.z, b4.w};
#pragma unroll
      for (int i = 0; i < 4; ++i)
#pragma unroll
        for (int j = 0; j < 4; ++j) acc[i][j] = fmaf(am[i], bm[j], acc[i][j]);
    }
    __syncthreads();
  }
#pragma unroll
  for (int i = 0; i < 4; ++i) {
    int r = row0 + ty * 4 + i;
    if (r >= M) break;
#pragma unroll
    for (int j = 0; j < 4; ++j) {
      int c = col0 + tx * 4 + j;
      if (c >= N) continue;
      float v = acc[i][j];
      if (BIAS) v += bias[c];
      if (ACT == 1) v = 0.5f * v * (1.f + erff(v * 0.70710678118654752f));
      if (ACT == 2) v = tanhf(v);
      float* cp = C + (size_t)r * N + c;
      if (ACCUM)
        *cp += v;
      else
        *cp = v;
    }
  }
}

// ---------------- RMSNorm (wave per row, 128 cols) ----------------
__global__ __launch_bounds__(256) void rmsnorm_k(const float* __restrict__ h,
                                                 const float* __restrict__ w,
                                                 float* __restrict__ o) {
  int lane = threadIdx.x & 63;
  int t = blockIdx.x * 4 + (threadIdx.x >> 6);
  const float* row = h + (size_t)t * DM;
  float x0 = row[lane], x1 = row[lane + 64];
  float ss = wave_sum64(x0 * x0 + x1 * x1);
  float r = 1.f / sqrtf(ss * (1.f / DM) + 1e-5f);
  o[(size_t)t * DM + lane] = x0 * r * w[lane];
  o[(size_t)t * DM + lane + 64] = x1 * r * w[lane + 64];
}

// ---------------- LayerNorm ----------------
__global__ __launch_bounds__(256) void layernorm_k(const float* __restrict__ h,
                                                   const float* __restrict__ w,
                                                   const float* __restrict__ b,
                                                   float* __restrict__ o) {
  int lane = threadIdx.x & 63;
  int t = blockIdx.x * 4 + (threadIdx.x >> 6);
  const float* row = h + (size_t)t * DM;
  float x0 = row[lane], x1 = row[lane + 64];
  float s = wave_sum64(x0 + x1);
  float ss = wave_sum64(x0 * x0 + x1 * x1);
  float m = s * (1.f / DM);
  float var = ss * (1.f / DM) - m * m;
  float r = 1.f / sqrtf(var + 1e-5f);
  o[(size_t)t * DM + lane] = (x0 - m) * r * w[lane] + b[lane];
  o[(size_t)t * DM + lane + 64] = (x1 - m) * r * w[lane + 64] + b[lane + 64];
}

// ---------------- causal depthwise conv (K=4) + SiLU ----------------
__global__ __launch_bounds__(256) void conv_silu_k(const float* __restrict__ xz,
                                                   const float* __restrict__ cw,
                                                   const float* __restrict__ cb,
                                                   float* __restrict__ xc) {
  int idx = blockIdx.x * 256 + threadIdx.x;  // e fast, t slow
  int e = idx & (EDM - 1);
  int t = idx >> 8;
  float acc = cb[e];
  const float* wp = cw + e * 4;
#pragma unroll
  for (int j = 0; j < 4; ++j) {
    int ts = t - 3 + j;
    if (ts >= 0) acc = fmaf(xz[(size_t)ts * 512 + e], wp[j], acc);
  }
  xc[idx] = acc / (1.f + expf(-acc));  // silu
}

// ---------------- delta = softplus(dlt @ dtw + dtb) ----------------
__global__ __launch_bounds__(256) void dt_k(const float* __restrict__ dbl,
                                            const float* __restrict__ dtw,
                                            const float* __restrict__ dtb,
                                            float* __restrict__ delta) {
  int idx = blockIdx.x * 256 + threadIdx.x;
  int e = idx & 255;
  int t = idx >> 8;
  const float* dl = dbl + (size_t)t * 40;
  float acc = dtb[e];
#pragma unroll
  for (int k = 0; k < 8; ++k) acc = fmaf(dl[k], dtw[k * 256 + e], acc);
  delta[idx] = fmaxf(acc, 0.f) + log1pf(expf(-fabsf(acc)));
}

// ---------------- scan pass 1: per-chunk (prod a, acc b) ----------------
__global__ __launch_bounds__(256) void scan1_k(const float* __restrict__ delta,
                                               const float* __restrict__ xc,
                                               const float* __restrict__ dbl,
                                               const float* __restrict__ alog,
                                               float* __restrict__ Aacc,
                                               float* __restrict__ Bacc) {
  int n = threadIdx.x & 15;
  int el = threadIdx.x >> 4;
  int e = blockIdx.y * 16 + el;
  int c = blockIdx.x;
  float Aen = -expf(alog[e * NS + n]);
  float aa = 1.f, bb = 0.f;
  int t0 = c * CSZ;
  for (int t = t0; t < t0 + CSZ; ++t) {
    float d = delta[(size_t)t * EDM + e];
    float da = expf(d * Aen);
    float b = d * xc[(size_t)t * EDM + e] * dbl[(size_t)t * 40 + 8 + n];
    bb = fmaf(da, bb, b);
    aa *= da;
  }
  int ch = blockIdx.y * 256 + threadIdx.x;  // == e*16+n
  Aacc[c * NCH + ch] = aa;
  Bacc[c * NCH + ch] = bb;
}

// ---------------- scan pass 2: inter-chunk scan ----------------
__global__ __launch_bounds__(256) void scan2_k(const float* __restrict__ Aacc,
                                               const float* __restrict__ Bacc,
                                               float* __restrict__ Hini) {
  int ch = blockIdx.x * 256 + threadIdx.x;
  float h = 0.f;
  for (int c = 0; c < NCHUNK; ++c) {
    Hini[c * NCH + ch] = h;
    h = fmaf(Aacc[c * NCH + ch], h, Bacc[c * NCH + ch]);
  }
}

// ---------------- scan pass 3: replay + y = (scan + dp*xc)*silu(z), y -> xc ----------------
__global__ __launch_bounds__(256) void scan3_k(const float* __restrict__ delta,
                                               float* __restrict__ xc,
                                               const float* __restrict__ dbl,
                                               const float* __restrict__ xz,
                                               const float* __restrict__ alog,
                                               const float* __restrict__ dp,
                                               const float* __restrict__ Hini) {
  int n = threadIdx.x & 15;
  int el = threadIdx.x >> 4;
  int e = blockIdx.y * 16 + el;
  int c = blockIdx.x;
  int ch = blockIdx.y * 256 + threadIdx.x;
  float Aen = -expf(alog[e * NS + n]);
  float h = Hini[c * NCH + ch];
  float dpe = dp[e];
  int t0 = c * CSZ;
  for (int t = t0; t < t0 + CSZ; ++t) {
    float d = delta[(size_t)t * EDM + e];
    float xcv = xc[(size_t)t * EDM + e];
    float da = expf(d * Aen);
    float b = d * xcv * dbl[(size_t)t * 40 + 8 + n];
    h = fmaf(da, h, b);
    float v = h * dbl[(size_t)t * 40 + 24 + n];
    v += __shfl_xor(v, 1);
    v += __shfl_xor(v, 2);
    v += __shfl_xor(v, 4);
    v += __shfl_xor(v, 8);
    if (n == 0) {
      float y = v + dpe * xcv;
      float z = xz[(size_t)t * 512 + 256 + e];
      y *= z / (1.f + expf(-z));
      xc[(size_t)t * EDM + e] = y;  // in-place: this (t,e) read only by this wave's 16-lane group
    }
  }
}

// ---------------- attention score tail: s[t] = t1[t,:] . w2 + b2 ----------------
__global__ __launch_bounds__(256) void att2_k(const float* __restrict__ t1,
                                              const float* __restrict__ w2,
                                              const float* __restrict__ b2,
                                              float* __restrict__ s) {
  int lane = threadIdx.x & 63;
  int t = blockIdx.x * 4 + (threadIdx.x >> 6);
  const float* row = t1 + (size_t)t * DM;
  float acc = fmaf(row[lane], w2[lane], row[lane + 64] * w2[lane + 64]);
  acc = wave_sum64(acc);
  if (lane == 0) s[t] = acc + b2[0];
}

// ---------------- softmax stats over L ----------------
__global__ __launch_bounds__(1024) void att_stats_k(const float* __restrict__ s,
                                                    float* __restrict__ stats) {
  __shared__ float red[16];
  int lane = threadIdx.x & 63, wid = threadIdx.x >> 6;
  float m = -1e30f;
  for (int i = threadIdx.x; i < LQ; i += 1024) m = fmaxf(m, s[i]);
  m = wave_max64(m);
  if (lane == 0) red[wid] = m;
  __syncthreads();
  if (threadIdx.x < 16) {
    float mm = red[threadIdx.x];
#pragma unroll
    for (int o = 8; o > 0; o >>= 1) mm = fmaxf(mm, __shfl_xor(mm, o));
    if (threadIdx.x == 0) red[0] = mm;
  }
  __syncthreads();
  float smax = red[0];
  __syncthreads();
  float sum = 0.f;
  for (int i = threadIdx.x; i < LQ; i += 1024) sum += expf(s[i] - smax);
  sum = wave_sum64(sum);
  if (lane == 0) red[wid] = sum;
  __syncthreads();
  if (threadIdx.x == 0) {
    float tot = 0.f;
    for (int i = 0; i < 16; ++i) tot += red[i];
    stats[0] = smax;
    stats[1] = tot;
  }
}

// ---------------- pooled[d] += sum_t exp(s-smax)*hn[t,d] ----------------
__global__ __launch_bounds__(128) void pooled_k(const float* __restrict__ s,
                                                const float* __restrict__ stats,
                                                const float* __restrict__ hn,
                                                float* __restrict__ pooled) {
  __shared__ float w[64];
  int t0 = blockIdx.x * 64;
  float smax = stats[0];
  if (threadIdx.x < 64) {
    int t = t0 + threadIdx.x;
    w[threadIdx.x] = (t < LQ) ? expf(s[t] - smax) : 0.f;
  }
  __syncthreads();
  int d = threadIdx.x;
  float acc = 0.f;
  int nmax = min(64, LQ - t0);
  for (int i = 0; i < nmax; ++i)
    acc = fmaf(w[i], hn[(size_t)(t0 + i) * DM + d], acc);
  atomicAdd(&pooled[d], acc);
}

// ---------------- classifier head + softmax + argmax ----------------
__global__ __launch_bounds__(128) void final_k(const float* __restrict__ pooled,
                                               const float* __restrict__ stats,
                                               const float* __restrict__ cls_w,
                                               const float* __restrict__ cls_b,
                                               float* __restrict__ out) {
  __shared__ float r0[2], r1[2];
  int lane = threadIdx.x & 63, wid = threadIdx.x >> 6;
  float p = pooled[threadIdx.x] / stats[1];
  float v0 = p * cls_w[threadIdx.x * 2 + 0];
  float v1 = p * cls_w[threadIdx.x * 2 + 1];
  v0 = wave_sum64(v0);
  v1 = wave_sum64(v1);
  if (lane == 0) {
    r0[wid] = v0;
    r1[wid] = v1;
  }
  __syncthreads();
  if (threadIdx.x == 0) {
    float L0 = r0[0] + r0[1] + cls_b[0];
    float L1 = r1[0] + r1[1] + cls_b[1];
    float mx = fmaxf(L0, L1);
    float e0 = expf(L0 - mx), e1 = expf(L1 - mx);
    float inv = 1.f / (e0 + e1);
    out[0] = L0;
    out[1] = L1;
    out[2] = e0 * inv;
    out[3] = e1 * inv;
    out[4] = (L1 > L0) ? 1.f : 0.f;  // argmax (tie -> 0, matches jnp)
  }
}

extern "C" void kernel_launch(void* const* d_in, const int* in_sizes, int n_in,
                              void* d_out, int out_size, void* d_ws,
                              size_t ws_size, hipStream_t stream) {
  const float* x = (const float*)d_in[0];
  // d_in[1] = coords (unused by reference output path)
  const float* fc1_w = (const float*)d_in[2];
  const float* fc1_b = (const float*)d_in[3];
  const float* rms_w = (const float*)d_in[4];
  const float* inproj_w = (const float*)d_in[5];
  const float* conv_w = (const float*)d_in[6];
  const float* conv_b = (const float*)d_in[7];
  const float* xproj_w = (const float*)d_in[8];
  const float* dt_w = (const float*)d_in[9];
  const float* dt_b = (const float*)d_in[10];
  const float* A_log = (const float*)d_in[11];
  const float* D_p = (const float*)d_in[12];
  const float* outproj_w = (const float*)d_in[13];
  const float* ln_w = (const float*)d_in[14];
  const float* ln_b = (const float*)d_in[15];
  const float* att_w1 = (const float*)d_in[16];
  const float* att_b1 = (const float*)d_in[17];
  const float* att_w2 = (const float*)d_in[18];
  const float* att_b2 = (const float*)d_in[19];
  const float* cls_w = (const float*)d_in[20];
  const float* cls_b = (const float*)d_in[21];
  float* out = (float*)d_out;

  float* ws = (float*)d_ws;
  float* h = ws;                      // L*128
  float* hn = h + LQ * DM;            // L*128 (rmsnorm out / layernorm out)
  float* xz = hn + LQ * DM;           // L*512 (xb | z)
  float* xc = xz + LQ * 512;          // L*256 (conv out, later y in-place)
  float* dbl = xc + LQ * EDM;         // L*40 (dlt|B|C); later att scores
  float* dlt = dbl + LQ * 40;         // L*256 (delta); later att t1
  float* Aacc = dlt + LQ * EDM;       // NCHUNK*4096
  float* Bacc = Aacc + NCHUNK * NCH;  // NCHUNK*4096
  float* Hini = Bacc + NCHUNK * NCH;  // NCHUNK*4096
  float* pooled = Hini + NCHUNK * NCH;  // 128
  float* stats = pooled + 128;          // 2

  hipMemsetAsync(pooled, 0, 128 * sizeof(float), stream);

  dim3 b256(256);
  // h = gelu(x @ fc1_w + fc1_b)
  gemm_k<1, true, false>
      <<<dim3(2, 188), b256, 0, stream>>>(x, fc1_w, fc1_b, h, LQ, DM, IN_D);

  for (int l = 0; l < 2; ++l) {
    rmsnorm_k<<<3000, b256, 0, stream>>>(h, rms_w + l * DM, hn);
    gemm_k<0, false, false><<<dim3(8, 188), b256, 0, stream>>>(
        hn, inproj_w + l * DM * 2 * EDM, nullptr, xz, LQ, 2 * EDM, DM);
    conv_silu_k<<<12000, b256, 0, stream>>>(xz, conv_w + l * EDM * 4,
                                            conv_b + l * EDM, xc);
    gemm_k<0, false, false><<<dim3(1, 188), b256, 0, stream>>>(
        xc, xproj_w + l * EDM * 40, nullptr, dbl, LQ, 40, EDM);
    dt_k<<<12000, b256, 0, stream>>>(dbl, dt_w + l * DTR * EDM, dt_b + l * EDM,
                                     dlt);
    scan1_k<<<dim3(NCHUNK, 16), b256, 0, stream>>>(
        dlt, xc, dbl, A_log + l * EDM * NS, Aacc, Bacc);
    scan2_k<<<16, b256, 0, stream>>>(Aacc, Bacc, Hini);
    scan3_k<<<dim3(NCHUNK, 16), b256, 0, stream>>>(
        dlt, xc, dbl, xz, A_log + l * EDM * NS, D_p + l * EDM, Hini);
    gemm_k<0, false, true><<<dim3(2, 188), b256, 0, stream>>>(
        xc, outproj_w + l * EDM * DM, nullptr, h, LQ, DM, EDM);
  }

  layernorm_k<<<3000, b256, 0, stream>>>(h, ln_w, ln_b, hn);
  // t1 = tanh(hn @ att_w1 + b1) -> reuse dlt buffer
  gemm_k<2, true, false>
      <<<dim3(2, 188), b256, 0, stream>>>(hn, att_w1, att_b1, dlt, LQ, DM, DM);
  att2_k<<<3000, b256, 0, stream>>>(dlt, att_w2, att_b2, dbl);
  att_stats_k<<<1, 1024, 0, stream>>>(dbl, stats);
  pooled_k<<<188, 128, 0, stream>>>(dbl, stats, hn, pooled);
  final_k<<<1, 128, 0, stream>>>(pooled, stats, cls_w, cls_b, out);
}